// Round 1
// baseline (9824.519 us; speedup 1.0000x reference)
//
#include <hip/hip_runtime.h>
#include <math.h>

// DrugGraphConv: 5000 graphs x 100 nodes x 400 edges, 5 TAGConv(K=2) layers
// DIMS = [74,70,65,60,55,37], gated softmax pooling per graph.
// Strategy: one block (256 thr) per graph; everything in LDS; fp32 end-to-end.

constexpr int NODES = 100;
constexpr int EDGES = 400;
constexpr int D0    = 74;
constexpr int NTHR  = 256;

template<int D_IN, int D_OUT>
__device__ __forceinline__ void tag_layer(
    float* bufA, float* bufB,
    const int* lsrc, const int* ldst, const float* nrm,
    const float* __restrict__ W, const float* __restrict__ Bv,
    int tid)
{
    constexpr int NG  = NTHR / D_OUT;            // thread groups (rows-of-nodes)
    constexpr int NPT = (NODES + NG - 1) / NG;   // nodes per thread
    const int col = tid % D_OUT;
    const int grp = tid / D_OUT;
    const bool active = (grp < NG);

    float acc[NPT];
#pragma unroll
    for (int j = 0; j < NPT; ++j) acc[j] = 0.f;

    // ---- GEMM block 0: feats = h (bufA, stride D_IN) ----
    if (active) {
        for (int k = 0; k < D_IN; ++k) {
            float w = W[k * D_OUT + col];          // coalesced across lanes
#pragma unroll
            for (int j = 0; j < NPT; ++j) {
                int node = grp + NG * j;
                if (node < NODES) acc[j] += bufA[node * D_IN + k] * w; // LDS broadcast
            }
        }
    }
    __syncthreads();

    // ---- hop 1: bufB = norm .* scatter_add(bufA[src]*norm[src] -> dst) ----
    for (int i = tid; i < NODES * D_IN; i += NTHR) bufB[i] = 0.f;
    __syncthreads();
    for (int idx = tid; idx < EDGES * D_IN; idx += NTHR) {
        int e = idx / D_IN;                        // const division
        int dim = idx - e * D_IN;
        int s = lsrc[e];
        atomicAdd(&bufB[ldst[e] * D_IN + dim], bufA[s * D_IN + dim] * nrm[s]);
    }
    __syncthreads();
    for (int i = tid; i < NODES * D_IN; i += NTHR) bufB[i] *= nrm[i / D_IN];
    __syncthreads();

    // ---- GEMM block 1: feats = hop1 (bufB) ----
    if (active) {
        for (int k = 0; k < D_IN; ++k) {
            float w = W[(D_IN + k) * D_OUT + col];
#pragma unroll
            for (int j = 0; j < NPT; ++j) {
                int node = grp + NG * j;
                if (node < NODES) acc[j] += bufB[node * D_IN + k] * w;
            }
        }
    }
    __syncthreads();

    // ---- hop 2: bufA = norm .* scatter_add(bufB[src]*norm[src] -> dst) ----
    for (int i = tid; i < NODES * D_IN; i += NTHR) bufA[i] = 0.f;
    __syncthreads();
    for (int idx = tid; idx < EDGES * D_IN; idx += NTHR) {
        int e = idx / D_IN;
        int dim = idx - e * D_IN;
        int s = lsrc[e];
        atomicAdd(&bufA[ldst[e] * D_IN + dim], bufB[s * D_IN + dim] * nrm[s]);
    }
    __syncthreads();
    for (int i = tid; i < NODES * D_IN; i += NTHR) bufA[i] *= nrm[i / D_IN];
    __syncthreads();

    // ---- GEMM block 2: feats = hop2 (bufA), then bias+ReLU ----
    if (active) {
        for (int k = 0; k < D_IN; ++k) {
            float w = W[(2 * D_IN + k) * D_OUT + col];
#pragma unroll
            for (int j = 0; j < NPT; ++j) {
                int node = grp + NG * j;
                if (node < NODES) acc[j] += bufA[node * D_IN + k] * w;
            }
        }
        float bias = Bv[col];
#pragma unroll
        for (int j = 0; j < NPT; ++j) acc[j] = fmaxf(acc[j] + bias, 0.f);
    }
    __syncthreads();   // all block-2 reads of bufA complete before overwrite

    // ---- write new h into bufA with stride D_OUT ----
    if (active) {
#pragma unroll
        for (int j = 0; j < NPT; ++j) {
            int node = grp + NG * j;
            if (node < NODES) bufA[node * D_OUT + col] = acc[j];
        }
    }
    __syncthreads();
}

__global__ __launch_bounds__(NTHR, 2)
void drug_graph_conv_kernel(
    const float* __restrict__ x,
    const int*   __restrict__ src,
    const int*   __restrict__ dst,
    const float* __restrict__ W0, const float* __restrict__ b0,
    const float* __restrict__ W1, const float* __restrict__ b1,
    const float* __restrict__ W2, const float* __restrict__ b2,
    const float* __restrict__ W3, const float* __restrict__ b3,
    const float* __restrict__ W4, const float* __restrict__ b4,
    const float* __restrict__ gate_w, const float* __restrict__ gate_b,
    float* __restrict__ out)
{
    __shared__ float bufA[NODES * D0];   // 29.6 KB
    __shared__ float bufB[NODES * D0];   // 29.6 KB
    __shared__ int   lsrc[EDGES];        // 1.6 KB
    __shared__ int   ldst[EDGES];        // 1.6 KB
    __shared__ float nrm[NODES];         // 0.4 KB
    __shared__ float gate[NODES];        // 0.4 KB   -> 63.2 KB total

    const int g   = blockIdx.x;
    const int tid = threadIdx.x;
    const int nbase = g * NODES;

    // load edge lists (localized), zero degree accumulator
    for (int e = tid; e < EDGES; e += NTHR) {
        lsrc[e] = src[g * EDGES + e] - nbase;
        ldst[e] = dst[g * EDGES + e] - nbase;
    }
    for (int i = tid; i < NODES; i += NTHR) nrm[i] = 0.f;
    __syncthreads();

    // in-degree via LDS atomics; stage x into bufA (stride 74) meanwhile
    for (int e = tid; e < EDGES; e += NTHR) atomicAdd(&nrm[ldst[e]], 1.0f);
    for (int i = tid; i < NODES * D0; i += NTHR) bufA[i] = x[nbase * D0 + i];
    __syncthreads();

    for (int i = tid; i < NODES; i += NTHR) nrm[i] = rsqrtf(fmaxf(nrm[i], 1.0f));
    __syncthreads();

    tag_layer<74, 70>(bufA, bufB, lsrc, ldst, nrm, W0, b0, tid);
    tag_layer<70, 65>(bufA, bufB, lsrc, ldst, nrm, W1, b1, tid);
    tag_layer<65, 60>(bufA, bufB, lsrc, ldst, nrm, W2, b2, tid);
    tag_layer<60, 55>(bufA, bufB, lsrc, ldst, nrm, W3, b3, tid);
    tag_layer<55, 37>(bufA, bufB, lsrc, ldst, nrm, W4, b4, tid);
    // bufA now holds final h: 100 x 37, stride 37

    // gate = h @ gate_w + gate_b  (one thread per node)
    if (tid < NODES) {
        float s = gate_b[0];
#pragma unroll
        for (int k = 0; k < 37; ++k) s += bufA[tid * 37 + k] * gate_w[k];
        gate[tid] = s;
    }
    __syncthreads();

    // softmax over the 100 nodes (computed redundantly per thread; LDS broadcast)
    float m = -INFINITY;
    for (int n = 0; n < NODES; ++n) m = fmaxf(m, gate[n]);
    float z = 0.f;
    for (int n = 0; n < NODES; ++n) z += __expf(gate[n] - m);

    // pooled[col] = sum_n alpha[n] * h[n][col]
    if (tid < 37) {
        float p = 0.f;
        for (int n = 0; n < NODES; ++n) p += bufA[n * 37 + tid] * __expf(gate[n] - m);
        out[g * 37 + tid] = p / z;
    }
}

extern "C" void kernel_launch(void* const* d_in, const int* in_sizes, int n_in,
                              void* d_out, int out_size, void* d_ws, size_t ws_size,
                              hipStream_t stream) {
    const float* x      = (const float*)d_in[0];
    const int*   src    = (const int*)  d_in[1];
    const int*   dst    = (const int*)  d_in[2];
    // d_in[3] = graph_ids (implicit: node / 100) — unused
    const float* W0 = (const float*)d_in[4];  const float* b0 = (const float*)d_in[5];
    const float* W1 = (const float*)d_in[6];  const float* b1 = (const float*)d_in[7];
    const float* W2 = (const float*)d_in[8];  const float* b2 = (const float*)d_in[9];
    const float* W3 = (const float*)d_in[10]; const float* b3 = (const float*)d_in[11];
    const float* W4 = (const float*)d_in[12]; const float* b4 = (const float*)d_in[13];
    const float* gw = (const float*)d_in[14]; const float* gb = (const float*)d_in[15];
    float* out = (float*)d_out;

    drug_graph_conv_kernel<<<5000, NTHR, 0, stream>>>(
        x, src, dst, W0, b0, W1, b1, W2, b2, W3, b3, W4, b4, gw, gb, out);
}